// Round 6
// baseline (628.935 us; speedup 1.0000x reference)
//
#include <hip/hip_runtime.h>
#include <stdint.h>

typedef __attribute__((ext_vector_type(8))) short bf16x8;
typedef __attribute__((ext_vector_type(4))) float f32x4;
typedef __attribute__((ext_vector_type(4))) unsigned int u32x4;
typedef __attribute__((ext_vector_type(4))) unsigned short u16x4;

typedef const void __attribute__((address_space(1))) gvoid_t;
typedef void __attribute__((address_space(3))) lvoid_t;

__device__ __forceinline__ unsigned short f2bf(float f) {
  union { float f; unsigned int u; } v; v.f = f;
  unsigned int u = v.u;
  u += 0x7fffu + ((u >> 16) & 1u);
  return (unsigned short)(u >> 16);
}
__device__ __forceinline__ float bf2f(unsigned short h) {
  union { unsigned int u; float f; } v; v.u = ((unsigned int)h) << 16;
  return v.f;
}
__device__ __forceinline__ void load_lds16(const void* g, void* l) {
  __builtin_amdgcn_global_load_lds((gvoid_t*)g, (lvoid_t*)l, 16, 0, 0);
}

#define GATE12() asm volatile("s_waitcnt vmcnt(12)" ::: "memory")
#define GATE4() asm volatile("s_waitcnt vmcnt(4)" ::: "memory")
#define GATE0() asm volatile("s_waitcnt vmcnt(0)" ::: "memory")
#define LGKM0() asm volatile("s_waitcnt lgkmcnt(0)" ::: "memory")
#define CFENCE() asm volatile("" ::: "memory")
#define BARRIER()                    \
  do {                               \
    asm volatile("" ::: "memory");   \
    __builtin_amdgcn_s_barrier();    \
    asm volatile("" ::: "memory");   \
  } while (0)

// ---------------- weights f32 -> bf16 (merged) ----------------
__global__ __launch_bounds__(256) void k_cvt3(const float* __restrict__ s0, int n0,
                                              const float* __restrict__ s1, int n1,
                                              const float* __restrict__ s2, int n2,
                                              unsigned short* __restrict__ d0,
                                              unsigned short* __restrict__ d1,
                                              unsigned short* __restrict__ d2) {
  int i = blockIdx.x * 256 + threadIdx.x;
  if (i < n0) { d0[i] = f2bf(s0[i]); return; }
  i -= n0;
  if (i < n1) { d1[i] = f2bf(s1[i]); return; }
  i -= n1;
  if (i < n2) d2[i] = f2bf(s2[i]);
}

// ---------------- mask -> 128-bit row bitmask ----------------
__global__ __launch_bounds__(256) void k_maskpack(const int* __restrict__ mask,
                                                  unsigned int* __restrict__ bm) {
  const int lane = threadIdx.x & 63;
  const int wv = (blockIdx.x << 2) + (threadIdx.x >> 6);
  const int r0 = wv * 16;
  for (int i = 0; i < 16; ++i) {
    const int r = r0 + i;
    const size_t base = (size_t)r * 100;
    const int c0 = mask[base + lane];
    int c1 = 0;
    if (lane < 36) c1 = mask[base + 64 + lane];
    const unsigned long long b0 = __ballot(c0 != 0);
    const unsigned long long b1 = __ballot(c1 != 0);
    if (lane == 0) {
      u32x4 v;
      v[0] = (unsigned int)b0; v[1] = (unsigned int)(b0 >> 32);
      v[2] = (unsigned int)b1; v[3] = (unsigned int)(b1 >> 32);
      *(u32x4*)(bm + (size_t)r * 4) = v;
    }
  }
}

// ---------------- gather + LN1 -> xn bf16 [rows][512] (chunk-local) ----------------
__global__ __launch_bounds__(256) void k_gather_ln(const int* __restrict__ conn,
                                                   const float* __restrict__ emb,
                                                   const float* __restrict__ g1,
                                                   const float* __restrict__ b1,
                                                   unsigned short* __restrict__ xn,
                                                   int row0) {
  const int lane = threadIdx.x & 63;
  const int wid = threadIdx.x >> 6;
  const int rloc = blockIdx.x * 4 + wid;
  const int row = row0 + rloc;
  const int rel = conn[row * 2 + 0];
  const int ent = conn[row * 2 + 1];
  const float4 r4 = *(const float4*)(emb + (size_t)rel * 256 + lane * 4);
  const float4 e4 = *(const float4*)(emb + (size_t)ent * 256 + lane * 4);
  float rv[4] = {r4.x, r4.y, r4.z, r4.w};
  float ev[4] = {e4.x, e4.y, e4.z, e4.w};
  float s = 0.f, ss = 0.f;
#pragma unroll
  for (int j = 0; j < 4; ++j) { s += rv[j] + ev[j]; ss += rv[j] * rv[j] + ev[j] * ev[j]; }
#pragma unroll
  for (int d = 1; d < 64; d <<= 1) { s += __shfl_xor(s, d, 64); ss += __shfl_xor(ss, d, 64); }
  const float mu = s * (1.f / 512.f);
  const float var = ss * (1.f / 512.f) - mu * mu;
  const float rs = rsqrtf(var + 1e-5f);
  const float4 ga = *(const float4*)(g1 + lane * 4);
  const float4 gb = *(const float4*)(g1 + 256 + lane * 4);
  const float4 ba = *(const float4*)(b1 + lane * 4);
  const float4 bb = *(const float4*)(b1 + 256 + lane * 4);
  float gav[4] = {ga.x, ga.y, ga.z, ga.w}, gbv[4] = {gb.x, gb.y, gb.z, gb.w};
  float bav[4] = {ba.x, ba.y, ba.z, ba.w}, bbv[4] = {bb.x, bb.y, bb.z, bb.w};
  u16x4 o0, o1;
#pragma unroll
  for (int j = 0; j < 4; ++j) {
    o0[j] = f2bf((rv[j] - mu) * rs * gav[j] + bav[j]);
    o1[j] = f2bf((ev[j] - mu) * rs * gbv[j] + bbv[j]);
  }
  unsigned short* orow = xn + (size_t)rloc * 512;
  *(u16x4*)(orow + lane * 4) = o0;
  *(u16x4*)(orow + 256 + lane * 4) = o1;
}

// ---- k_gemm5: producer-consumer GEMM, 256x128 tile, 4-slot LDS ring, no loop barriers ----
// 384 threads: waves 0-3 consume (wave-tile 128x64), waves 4-5 produce (global_load_lds).
// C[M,N] = A[M,K]*W[N,K]^T + bias, bf16 out. M%256==0, N%128==0, K%32==0, K/32 in [2,32].
__global__ __launch_bounds__(384) void k_gemm5(const unsigned short* __restrict__ A,
                                               const unsigned short* __restrict__ W,
                                               const float* __restrict__ bias,
                                               unsigned short* __restrict__ C,
                                               int N, int K, int ntiles, int nwg) {
  __shared__ __align__(16) unsigned short slotA[4][256 * 32];
  __shared__ __align__(16) unsigned short slotB[4][128 * 32];
  __shared__ int rdy[32];
  __shared__ int done[32];

  // bijective XCD swizzle
  const int orig = blockIdx.x;
  const int q = nwg >> 3, r = nwg & 7;
  const int xcd = orig & 7, idx = orig >> 3;
  const int wg = (xcd < r ? xcd * (q + 1) : r * (q + 1) + (xcd - r) * q) + idx;
  const int mtile = wg / ntiles, ntile = wg % ntiles;

  const int t = threadIdx.x, lane = t & 63, wid = t >> 6;
  const size_t Abase = (size_t)mtile * 256 * K;
  const size_t Wbase = (size_t)ntile * 128 * K;
  const int NT = K >> 5;

  if (t < 32) { rdy[t] = 0; done[t] = 0; }
  BARRIER();

  if (wid >= 4) {
    // ---------------- producers: 2 waves, 12 loads each per slice ----------------
    const int pt = t - 256;  // 0..127
    for (int s = 0; s < NT; ++s) {
      if (s >= 4) {
        volatile int* dv = done;
        while (dv[s - 4] < 4) __builtin_amdgcn_s_sleep(1);
        CFENCE();
      }
      const int slot = s & 3;
#pragma unroll
      for (int it = 0; it < 8; ++it) {
        const int row = it * 32 + (pt >> 2);
        const int cl = (pt & 3) ^ ((row >> 1) & 3);
        load_lds16(A + Abase + (size_t)row * K + s * 32 + cl * 8, &slotA[slot][it * 1024 + pt * 8]);
      }
#pragma unroll
      for (int it = 0; it < 4; ++it) {
        const int row = it * 32 + (pt >> 2);
        const int cl = (pt & 3) ^ ((row >> 1) & 3);
        load_lds16(W + Wbase + (size_t)row * K + s * 32 + cl * 8, &slotB[slot][it * 1024 + pt * 8]);
      }
      if (s >= 1) {  // publish s-1: 12 newest (slice s) may fly, older landed
        GATE12();
        atomicAdd(&rdy[s - 1], 1);
        CFENCE();
      }
    }
    GATE0();
    atomicAdd(&rdy[NT - 1], 1);
    return;
  }

  // ---------------- consumers: 4 waves, wave-tile 128x64 ----------------
  const int wm = wid >> 1, wn = wid & 1;
  f32x4 acc[8][4];
#pragma unroll
  for (int i = 0; i < 8; ++i)
#pragma unroll
    for (int j = 0; j < 4; ++j) acc[i][j] = (f32x4){0.f, 0.f, 0.f, 0.f};

  for (int s = 0; s < NT; ++s) {
    {
      volatile int* rv = rdy;
      while (rv[s] < 2) __builtin_amdgcn_s_sleep(1);
      CFENCE();
    }
    const int slot = s & 3;
    bf16x8 af[8], br[4];
#pragma unroll
    for (int mi = 0; mi < 8; ++mi) {
      const int row = wm * 128 + mi * 16 + (lane & 15);
      const int st = (lane >> 4) ^ ((row >> 1) & 3);
      af[mi] = *(const bf16x8*)&slotA[slot][row * 32 + st * 8];
    }
#pragma unroll
    for (int ni = 0; ni < 4; ++ni) {
      const int row = wn * 64 + ni * 16 + (lane & 15);
      const int st = (lane >> 4) ^ ((row >> 1) & 3);
      br[ni] = *(const bf16x8*)&slotB[slot][row * 32 + st * 8];
    }
#pragma unroll
    for (int mi = 0; mi < 8; ++mi)
#pragma unroll
      for (int ni = 0; ni < 4; ++ni)
        acc[mi][ni] = __builtin_amdgcn_mfma_f32_16x16x32_bf16(br[ni], af[mi], acc[mi][ni], 0, 0, 0);
    LGKM0();
    atomicAdd(&done[s], 1);
    CFENCE();
  }

  // epilogue: swapped-operand layout -> lane holds 4 consecutive cols per frag
#pragma unroll
  for (int ni = 0; ni < 4; ++ni) {
    const int colb = ntile * 128 + wn * 64 + ni * 16 + ((lane >> 4) << 2);
    const float4 bv = *(const float4*)(bias + colb);
#pragma unroll
    for (int mi = 0; mi < 8; ++mi) {
      const int row = mtile * 256 + wm * 128 + mi * 16 + (lane & 15);
      const unsigned int lo =
          (unsigned int)f2bf(acc[mi][ni][0] + bv.x) | ((unsigned int)f2bf(acc[mi][ni][1] + bv.y) << 16);
      const unsigned int hi =
          (unsigned int)f2bf(acc[mi][ni][2] + bv.z) | ((unsigned int)f2bf(acc[mi][ni][3] + bv.w) << 16);
      uint2 pk; pk.x = lo; pk.y = hi;
      *(uint2*)(C + (size_t)row * N + colb) = pk;
    }
  }
}

// ---- GEMM 128x128, BK=32, triple-buffered (small shapes: proj-z, fc) ----
template <typename CT>
__global__ __launch_bounds__(256) void k_gemm3(const unsigned short* __restrict__ A,
                                               const unsigned short* __restrict__ W,
                                               const float* __restrict__ bias,
                                               CT* __restrict__ C,
                                               int N, int K, int ntiles, int nwg) {
  __shared__ __align__(16) unsigned short ldsA[3][128 * 32];
  __shared__ __align__(16) unsigned short ldsB[3][128 * 32];

  const int orig = blockIdx.x;
  const int q = nwg >> 3, r = nwg & 7;
  const int xcd = orig & 7, idx = orig >> 3;
  const int wg = (xcd < r ? xcd * (q + 1) : r * (q + 1) + (xcd - r) * q) + idx;
  const int mtile = wg / ntiles, ntile = wg % ntiles;

  const int t = threadIdx.x, lane = t & 63, wid = t >> 6;
  const int wm = wid >> 1, wn = wid & 1;
  const size_t Abase = (size_t)mtile * 128 * K;
  const size_t Wbase = (size_t)ntile * 128 * K;
  const int NT = K >> 5;

  f32x4 acc[4][4];
#pragma unroll
  for (int i = 0; i < 4; ++i)
#pragma unroll
    for (int j = 0; j < 4; ++j) acc[i][j] = (f32x4){0.f, 0.f, 0.f, 0.f};

  const int sr0 = t >> 2;
  auto stage = [&](int buf, int kt) {
#pragma unroll
    for (int it = 0; it < 2; ++it) {
      const int row = it * 64 + sr0;
      const int cl = (t & 3) ^ ((row >> 1) & 3);
      load_lds16(A + Abase + (size_t)row * K + kt * 32 + cl * 8, &ldsA[buf][it * 2048 + t * 8]);
    }
#pragma unroll
    for (int it = 0; it < 2; ++it) {
      const int row = it * 64 + sr0;
      const int cl = (t & 3) ^ ((row >> 1) & 3);
      load_lds16(W + Wbase + (size_t)row * K + kt * 32 + cl * 8, &ldsB[buf][it * 2048 + t * 8]);
    }
  };

  stage(0, 0);
  stage(1, 1);

  int cur = 0;
  for (int kt = 0; kt < NT; ++kt) {
    if (kt + 1 < NT) { GATE4(); } else { GATE0(); }
    BARRIER();
    if (kt + 2 < NT) {
      int s2 = cur + 2; if (s2 >= 3) s2 -= 3;
      stage(s2, kt + 2);
    }
    bf16x8 af[4], bfr[4];
#pragma unroll
    for (int mi = 0; mi < 4; ++mi) {
      const int row = wm * 64 + mi * 16 + (lane & 15);
      const int st = (lane >> 4) ^ ((row >> 1) & 3);
      af[mi] = *(const bf16x8*)&ldsA[cur][row * 32 + st * 8];
    }
#pragma unroll
    for (int ni = 0; ni < 4; ++ni) {
      const int row = wn * 64 + ni * 16 + (lane & 15);
      const int st = (lane >> 4) ^ ((row >> 1) & 3);
      bfr[ni] = *(const bf16x8*)&ldsB[cur][row * 32 + st * 8];
    }
#pragma unroll
    for (int mi = 0; mi < 4; ++mi)
#pragma unroll
      for (int ni = 0; ni < 4; ++ni)
        acc[mi][ni] = __builtin_amdgcn_mfma_f32_16x16x32_bf16(af[mi], bfr[ni], acc[mi][ni], 0, 0, 0);
    cur = (cur + 1 == 3) ? 0 : cur + 1;
  }

#pragma unroll
  for (int ni = 0; ni < 4; ++ni) {
    const int col = ntile * 128 + wn * 64 + ni * 16 + (lane & 15);
    const float bv = bias[col];
#pragma unroll
    for (int mi = 0; mi < 4; ++mi) {
      const int row0 = mtile * 128 + wm * 64 + mi * 16 + ((lane >> 4) << 2);
#pragma unroll
      for (int r2 = 0; r2 < 4; ++r2) {
        const float ov = acc[mi][ni][r2] + bv;
        if constexpr (sizeof(CT) == 2)
          C[(size_t)(row0 + r2) * N + col] = (CT)f2bf(ov);
        else
          C[(size_t)(row0 + r2) * N + col] = (CT)ov;
      }
    }
  }
}

// ---------------- fused attention per (b,h), 62KB static LDS ----------------
__global__ __launch_bounds__(512) void k_attn(const unsigned short* __restrict__ qkv,
                                              const unsigned int* __restrict__ bm,
                                              unsigned short* __restrict__ y,
                                              float* __restrict__ am, int b0) {
  __shared__ __align__(16) unsigned short A_lds[128 * 128];   // K, then V^T
  __shared__ __align__(16) unsigned short P_lds[7 * 16 * 128];
  __shared__ float am_s[112];
  const int t = threadIdx.x, lane = t & 63, w = t >> 6;
  const int bl = blockIdx.x >> 2, h = blockIdx.x & 3;
  const int bg = b0 + bl;
  const unsigned short* qk = qkv + (size_t)bl * 153600;

  if (t < 112) am_s[t] = 0.f;

#pragma unroll
  for (int j = 0; j < 4; ++j) {
    const int row = j * 32 + w * 4 + (lane >> 4);
    if (row < 100) {
      const int c = (lane & 15) ^ (row & 7);
      load_lds16(qk + (size_t)row * 1536 + 512 + h * 128 + c * 8,
                 &A_lds[j * 4096 + w * 512 + lane * 8]);
    }
  }
  u32x4 vv[4];
#pragma unroll
  for (int p = 0; p < 4; ++p) {
    const int vm = p * 32 + (t >> 4);
    const u32x4 z = {0u, 0u, 0u, 0u};
    vv[p] = (vm < 100) ? *(const u32x4*)(qk + (size_t)vm * 1536 + 1024 + h * 128 + (t & 15) * 8) : z;
  }
  bf16x8 qf[4];
  {
    const int qrow = w * 16 + (lane & 15);
    const bool qv = (w < 7) && (qrow < 100);
#pragma unroll
    for (int kk = 0; kk < 4; ++kk) {
      const bf16x8 z = {0, 0, 0, 0, 0, 0, 0, 0};
      qf[kk] = qv ? *(const bf16x8*)(qk + (size_t)qrow * 1536 + h * 128 + kk * 32 + (lane >> 4) * 8) : z;
    }
  }
  if (t < 192) {
    const u32x4 z = {0u, 0u, 0u, 0u};
    *(u32x4*)&A_lds[(100 + (t >> 4)) * 128 + (t & 15) * 8] = z;
  }
  __syncthreads();

  f32x4 sa[7];
#pragma unroll
  for (int ni = 0; ni < 7; ++ni) sa[ni] = (f32x4){0.f, 0.f, 0.f, 0.f};
  if (w < 7) {
#pragma unroll
    for (int kk = 0; kk < 4; ++kk)
#pragma unroll
      for (int ni = 0; ni < 7; ++ni) {
        const int row = ni * 16 + (lane & 15);
        const int c = (kk * 4 + (lane >> 4)) ^ (row & 7);
        const bf16x8 kf = *(const bf16x8*)&A_lds[row * 128 + (c << 3)];
        sa[ni] = __builtin_amdgcn_mfma_f32_16x16x32_bf16(qf[kk], kf, sa[ni], 0, 0, 0);
      }
  }
  __syncthreads();

#pragma unroll
  for (int p = 0; p < 4; ++p) {
    const int vm = p * 32 + (t >> 4);
    unsigned short tmp[8];
    *(u32x4*)tmp = vv[p];
#pragma unroll
    for (int jj = 0; jj < 8; ++jj) {
      const int d = (lane & 15) * 8 + jj;
      const int swz = (vm >> 3) ^ (((d >> 3) ^ d) & 7);
      A_lds[d * 128 + swz * 8 + (vm & 7)] = tmp[jj];
    }
  }

  if (w < 7) {
    const float scale = 0.08838834764831843f;
    float psum[7] = {0.f, 0.f, 0.f, 0.f, 0.f, 0.f, 0.f};
#pragma unroll
    for (int r = 0; r < 4; ++r) {
      const int lr = (lane >> 4) * 4 + r;
      const int qrow = w * 16 + lr;
      if (qrow < 100) {
        const u32x4 bmv = *(const u32x4*)(bm + ((size_t)bg * 100 + qrow) * 4);
        float x[7];
#pragma unroll
        for (int ni = 0; ni < 7; ++ni) {
          const int col = ni * 16 + (lane & 15);
          const unsigned int bit = (bmv[ni >> 1] >> (((ni & 1) << 4) + (lane & 15))) & 1u;
          x[ni] = (col < 100) ? (bit ? sa[ni][r] * scale : -1e9f) : -1e30f;
        }
        float mx = x[0];
#pragma unroll
        for (int ni = 1; ni < 7; ++ni) mx = fmaxf(mx, x[ni]);
#pragma unroll
        for (int dd = 1; dd < 16; dd <<= 1) mx = fmaxf(mx, __shfl_xor(mx, dd, 64));
        float e[7], sum = 0.f;
#pragma unroll
        for (int ni = 0; ni < 7; ++ni) { e[ni] = __expf(x[ni] - mx); sum += e[ni]; }
#pragma unroll
        for (int dd = 1; dd < 16; dd <<= 1) sum += __shfl_xor(sum, dd, 64);
        const float inv = 1.f / sum;
#pragma unroll
        for (int ni = 0; ni < 7; ++ni) {
          const float pv = e[ni] * inv;
          psum[ni] += pv;
          const int col = ni * 16 + (lane & 15);
          const int c = (col >> 3) ^ (lr & 7);
          P_lds[w * 2048 + lr * 128 + c * 8 + (col & 7)] = f2bf(pv);
        }
      } else {
#pragma unroll
        for (int ni = 0; ni < 7; ++ni) {
          const int col = ni * 16 + (lane & 15);
          const int c = (col >> 3) ^ (lr & 7);
          P_lds[w * 2048 + lr * 128 + c * 8 + (col & 7)] = 0;
        }
      }
    }
    if (lane < 32) {
      const int lr = lane & 15;
      const int c = (14 + (lane >> 4)) ^ (lr & 7);
      const u32x4 z = {0u, 0u, 0u, 0u};
      *(u32x4*)&P_lds[w * 2048 + lr * 128 + c * 8] = z;
    }
#pragma unroll
    for (int ni = 0; ni < 7; ++ni) atomicAdd(&am_s[ni * 16 + (lane & 15)], psum[ni]);
  }
  __syncthreads();

  if (t < 100) am[((size_t)bg * 4 + h) * 100 + t] = am_s[t] * 0.01f;

  if (w < 7) {
#pragma unroll
    for (int dt = 0; dt < 8; ++dt) {
      f32x4 acc = {0.f, 0.f, 0.f, 0.f};
#pragma unroll
      for (int kk = 0; kk < 4; ++kk) {
        const int c = kk * 4 + (lane >> 4);
        const bf16x8 pf = *(const bf16x8*)&P_lds[w * 2048 + (lane & 15) * 128 + ((c ^ (lane & 7)) << 3)];
        const int d = dt * 16 + (lane & 15);
        const int cv = c ^ (((d >> 3) ^ d) & 7);
        const bf16x8 vf = *(const bf16x8*)&A_lds[d * 128 + (cv << 3)];
        acc = __builtin_amdgcn_mfma_f32_16x16x32_bf16(pf, vf, acc, 0, 0, 0);
      }
      const int d = dt * 16 + (lane & 15);
#pragma unroll
      for (int r = 0; r < 4; ++r) {
        const int qrow = w * 16 + (lane >> 4) * 4 + r;
        if (qrow < 100)
          y[((size_t)bl * 100 + qrow) * 512 + h * 128 + d] = f2bf(acc[r]);
      }
    }
  }
}

// ---------------- z = am^T y  (per b: [4][512]) -> bf16 rows (b*4+h) ----------------
__global__ __launch_bounds__(256) void k_z(const float* __restrict__ am,
                                           const unsigned short* __restrict__ y,
                                           unsigned short* __restrict__ zb, int b0) {
  __shared__ float ams[400];
  const int bl = blockIdx.x, t = threadIdx.x;
  const int bg = b0 + bl;
  for (int i = t; i < 400; i += 256) ams[i] = am[(size_t)bg * 400 + i];
  __syncthreads();
  float a0[4] = {0, 0, 0, 0}, a1[4] = {0, 0, 0, 0};
  const unsigned short* yb = y + (size_t)bl * 100 * 512 + t * 2;
  for (int n = 0; n < 100; ++n) {
    const unsigned int u = *(const unsigned int*)(yb + (size_t)n * 512);
    const float v0 = bf2f((unsigned short)(u & 0xffffu));
    const float v1 = bf2f((unsigned short)(u >> 16));
#pragma unroll
    for (int hh = 0; hh < 4; ++hh) {
      const float ww = ams[hh * 100 + n];
      a0[hh] += ww * v0;
      a1[hh] += ww * v1;
    }
  }
#pragma unroll
  for (int hh = 0; hh < 4; ++hh) {
    const unsigned int pk = (unsigned int)f2bf(a0[hh]) | ((unsigned int)f2bf(a1[hh]) << 16);
    *(unsigned int*)(zb + ((size_t)(bl * 4 + hh)) * 512 + 2 * t) = pk;
  }
}

// ---------------- LN2 per row (wave-per-row) ----------------
__global__ __launch_bounds__(256) void k_ln2(const unsigned short* __restrict__ wcb,
                                             const float* __restrict__ g2,
                                             const float* __restrict__ b2,
                                             unsigned short* __restrict__ wcn) {
  const int t = threadIdx.x, lane = t & 63, w = t >> 6;
  const int row = blockIdx.x * 4 + w;
  const u32x4 pv = *(const u32x4*)(wcb + (size_t)row * 512 + lane * 8);
  float v[8];
#pragma unroll
  for (int j = 0; j < 4; ++j) {
    v[2 * j] = bf2f((unsigned short)(pv[j] & 0xffffu));
    v[2 * j + 1] = bf2f((unsigned short)(pv[j] >> 16));
  }
  float s = 0.f, ss = 0.f;
#pragma unroll
  for (int j = 0; j < 8; ++j) { s += v[j]; ss += v[j] * v[j]; }
#pragma unroll
  for (int d = 1; d < 64; d <<= 1) { s += __shfl_xor(s, d, 64); ss += __shfl_xor(ss, d, 64); }
  const float mu = s * (1.f / 512.f);
  const float var = ss * (1.f / 512.f) - mu * mu;
  const float rs = rsqrtf(var + 1e-5f);
  const float4 ga = *(const float4*)(g2 + lane * 8);
  const float4 gb = *(const float4*)(g2 + lane * 8 + 4);
  const float4 ba = *(const float4*)(b2 + lane * 8);
  const float4 bb = *(const float4*)(b2 + lane * 8 + 4);
  const float gv[8] = {ga.x, ga.y, ga.z, ga.w, gb.x, gb.y, gb.z, gb.w};
  const float bv[8] = {ba.x, ba.y, ba.z, ba.w, bb.x, bb.y, bb.z, bb.w};
  u32x4 ov;
#pragma unroll
  for (int j = 0; j < 4; ++j) {
    const unsigned short lo = f2bf((v[2 * j] - mu) * rs * gv[2 * j] + bv[2 * j]);
    const unsigned short hi = f2bf((v[2 * j + 1] - mu) * rs * gv[2 * j + 1] + bv[2 * j + 1]);
    ov[j] = (unsigned int)lo | ((unsigned int)hi << 16);
  }
  *(u32x4*)(wcn + (size_t)row * 512 + lane * 8) = ov;
}

extern "C" void kernel_launch(void* const* d_in, const int* in_sizes, int n_in,
                              void* d_out, int out_size, void* d_ws, size_t ws_size,
                              hipStream_t stream) {
  const int* conn = (const int*)d_in[0];
  const int* mask = (const int*)d_in[1];
  const float* emb = (const float*)d_in[2];
  const float* qkv_w = (const float*)d_in[3];
  const float* qkv_b = (const float*)d_in[4];
  const float* proj_w = (const float*)d_in[5];
  const float* proj_b = (const float*)d_in[6];
  const float* ln1g = (const float*)d_in[7];
  const float* ln1b = (const float*)d_in[8];
  const float* ln2g = (const float*)d_in[9];
  const float* ln2b = (const float*)d_in[10];
  const float* fc_w = (const float*)d_in[11];
  const float* fc_b = (const float*)d_in[12];
  float* out = (float*)d_out;

  size_t off = 0;
  auto alloc = [&](size_t bytes) {
    void* p = (char*)d_ws + off;
    off += (bytes + 255) & ~(size_t)255;
    return p;
  };
  unsigned short* w_qkv = (unsigned short*)alloc((size_t)1536 * 512 * 2);
  unsigned short* w_proj = (unsigned short*)alloc((size_t)512 * 512 * 2);
  unsigned short* w_fc = (unsigned short*)alloc((size_t)256 * 512 * 2);
  float* am = (float*)alloc((size_t)1024 * 400 * 4);
  unsigned int* bmb = (unsigned int*)alloc((size_t)102400 * 16);
  const size_t fixed = off;

  int CB = 1024;
  while (CB > 64) {
    size_t need = fixed + (size_t)CB * 4 * 512 * 2 * 3 + (size_t)CB * 100 * 512 * 2 +
                  (size_t)CB * 100 * 1536 * 2 + 8192;
    if (need <= ws_size) break;
    CB >>= 1;
  }
  unsigned short* zbuf = (unsigned short*)alloc((size_t)CB * 4 * 512 * 2);
  unsigned short* wcb = (unsigned short*)alloc((size_t)CB * 4 * 512 * 2);
  unsigned short* wcn = (unsigned short*)alloc((size_t)CB * 4 * 512 * 2);
  unsigned short* xn = (unsigned short*)alloc((size_t)CB * 100 * 512 * 2);    // also y
  unsigned short* qkvb = (unsigned short*)alloc((size_t)CB * 100 * 1536 * 2);

  k_cvt3<<<(786432 + 262144 + 131072 + 255) / 256, 256, 0, stream>>>(
      qkv_w, 786432, proj_w, 262144, fc_w, 131072, w_qkv, w_proj, w_fc);
  k_maskpack<<<1600, 256, 0, stream>>>(mask, bmb);

  for (int b0 = 0; b0 < 1024; b0 += CB) {
    const int mt256 = CB * 100 / 256;   // QKV: 256-row tiles
    const int zt = CB * 4 / 128;        // small GEMMs: 128-row tiles
    k_gather_ln<<<CB * 25, 256, 0, stream>>>(conn, emb, ln1g, ln1b, xn, b0 * 100);
    k_gemm5<<<12 * mt256, 384, 0, stream>>>(xn, w_qkv, qkv_b, qkvb, 1536, 512, 12, 12 * mt256);
    k_attn<<<CB * 4, 512, 0, stream>>>(qkvb, bmb, xn /*y*/, am, b0);
    k_z<<<CB, 256, 0, stream>>>(am, xn /*y*/, zbuf, b0);
    k_gemm3<unsigned short><<<4 * zt, 256, 0, stream>>>(zbuf, w_proj, proj_b, wcb, 512, 512, 4, 4 * zt);
    k_ln2<<<CB, 256, 0, stream>>>(wcb, ln2g, ln2b, wcn);
    k_gemm3<float><<<2 * zt, 256, 0, stream>>>(wcn, w_fc, fc_b, out + (size_t)b0 * 1024, 256, 512, 2, 2 * zt);
  }
}

// Round 7
// 570.092 us; speedup vs baseline: 1.1032x; 1.1032x over previous
//
#include <hip/hip_runtime.h>
#include <stdint.h>

typedef __attribute__((ext_vector_type(8))) short bf16x8;
typedef __attribute__((ext_vector_type(4))) float f32x4;
typedef __attribute__((ext_vector_type(4))) unsigned int u32x4;
typedef __attribute__((ext_vector_type(4))) unsigned short u16x4;

typedef const void __attribute__((address_space(1))) gvoid_t;
typedef void __attribute__((address_space(3))) lvoid_t;

__device__ __forceinline__ unsigned short f2bf(float f) {
  union { float f; unsigned int u; } v; v.f = f;
  unsigned int u = v.u;
  u += 0x7fffu + ((u >> 16) & 1u);
  return (unsigned short)(u >> 16);
}
__device__ __forceinline__ float bf2f(unsigned short h) {
  union { unsigned int u; float f; } v; v.u = ((unsigned int)h) << 16;
  return v.f;
}
__device__ __forceinline__ void load_lds16(const void* g, void* l) {
  __builtin_amdgcn_global_load_lds((gvoid_t*)g, (lvoid_t*)l, 16, 0, 0);
}

#define GATE4() asm volatile("s_waitcnt vmcnt(4)" ::: "memory")
#define GATE0() asm volatile("s_waitcnt vmcnt(0)" ::: "memory")
#define BARRIER()                    \
  do {                               \
    asm volatile("" ::: "memory");   \
    __builtin_amdgcn_s_barrier();    \
    asm volatile("" ::: "memory");   \
  } while (0)

// ---------------- weights f32 -> bf16 (merged) ----------------
__global__ __launch_bounds__(256) void k_cvt3(const float* __restrict__ s0, int n0,
                                              const float* __restrict__ s1, int n1,
                                              const float* __restrict__ s2, int n2,
                                              unsigned short* __restrict__ d0,
                                              unsigned short* __restrict__ d1,
                                              unsigned short* __restrict__ d2) {
  int i = blockIdx.x * 256 + threadIdx.x;
  if (i < n0) { d0[i] = f2bf(s0[i]); return; }
  i -= n0;
  if (i < n1) { d1[i] = f2bf(s1[i]); return; }
  i -= n1;
  if (i < n2) d2[i] = f2bf(s2[i]);
}

// ---------------- mask -> 128-bit row bitmask ----------------
__global__ __launch_bounds__(256) void k_maskpack(const int* __restrict__ mask,
                                                  unsigned int* __restrict__ bm) {
  const int lane = threadIdx.x & 63;
  const int wv = (blockIdx.x << 2) + (threadIdx.x >> 6);
  const int r0 = wv * 16;
  for (int i = 0; i < 16; ++i) {
    const int r = r0 + i;
    const size_t base = (size_t)r * 100;
    const int c0 = mask[base + lane];
    int c1 = 0;
    if (lane < 36) c1 = mask[base + 64 + lane];
    const unsigned long long b0 = __ballot(c0 != 0);
    const unsigned long long b1 = __ballot(c1 != 0);
    if (lane == 0) {
      u32x4 v;
      v[0] = (unsigned int)b0; v[1] = (unsigned int)(b0 >> 32);
      v[2] = (unsigned int)b1; v[3] = (unsigned int)(b1 >> 32);
      *(u32x4*)(bm + (size_t)r * 4) = v;
    }
  }
}

// ---------------- gather + LN1 -> xn bf16 [rows][512] (chunk-local) ----------------
__global__ __launch_bounds__(256) void k_gather_ln(const int* __restrict__ conn,
                                                   const float* __restrict__ emb,
                                                   const float* __restrict__ g1,
                                                   const float* __restrict__ b1,
                                                   unsigned short* __restrict__ xn,
                                                   int row0) {
  const int lane = threadIdx.x & 63;
  const int wid = threadIdx.x >> 6;
  const int rloc = blockIdx.x * 4 + wid;
  const int row = row0 + rloc;
  const int rel = conn[row * 2 + 0];
  const int ent = conn[row * 2 + 1];
  const float4 r4 = *(const float4*)(emb + (size_t)rel * 256 + lane * 4);
  const float4 e4 = *(const float4*)(emb + (size_t)ent * 256 + lane * 4);
  float rv[4] = {r4.x, r4.y, r4.z, r4.w};
  float ev[4] = {e4.x, e4.y, e4.z, e4.w};
  float s = 0.f, ss = 0.f;
#pragma unroll
  for (int j = 0; j < 4; ++j) { s += rv[j] + ev[j]; ss += rv[j] * rv[j] + ev[j] * ev[j]; }
#pragma unroll
  for (int d = 1; d < 64; d <<= 1) { s += __shfl_xor(s, d, 64); ss += __shfl_xor(ss, d, 64); }
  const float mu = s * (1.f / 512.f);
  const float var = ss * (1.f / 512.f) - mu * mu;
  const float rs = rsqrtf(var + 1e-5f);
  const float4 ga = *(const float4*)(g1 + lane * 4);
  const float4 gb = *(const float4*)(g1 + 256 + lane * 4);
  const float4 ba = *(const float4*)(b1 + lane * 4);
  const float4 bb = *(const float4*)(b1 + 256 + lane * 4);
  float gav[4] = {ga.x, ga.y, ga.z, ga.w}, gbv[4] = {gb.x, gb.y, gb.z, gb.w};
  float bav[4] = {ba.x, ba.y, ba.z, ba.w}, bbv[4] = {bb.x, bb.y, bb.z, bb.w};
  u16x4 o0, o1;
#pragma unroll
  for (int j = 0; j < 4; ++j) {
    o0[j] = f2bf((rv[j] - mu) * rs * gav[j] + bav[j]);
    o1[j] = f2bf((ev[j] - mu) * rs * gbv[j] + bbv[j]);
  }
  unsigned short* orow = xn + (size_t)rloc * 512;
  *(u16x4*)(orow + lane * 4) = o0;
  *(u16x4*)(orow + 256 + lane * 4) = o1;
}

// ---- k_gemm8: 256x256 tile, BK=64, 8 waves (2Mx4N), 8-phase counted-vmcnt schedule ----
// C[M,N] = A[M,K]*W[N,K]^T + bias, bf16 out. M%256==0, N%256==0, K%128==0 (NT even).
// LDS [2buf][2half][128][64] per operand; stage map keeps >=1-phase margin between a
// half's last ds_read and its overwrite; vmcnt(4) gates at p4/p8 only (never 0 in loop).
__global__ __launch_bounds__(512, 2) void k_gemm8(const unsigned short* __restrict__ A,
                                                  const unsigned short* __restrict__ W,
                                                  const float* __restrict__ bias,
                                                  unsigned short* __restrict__ C,
                                                  int N, int K, int ntiles, int nwg) {
  __shared__ __align__(16) unsigned short ldsA[2][2][128 * 64];
  __shared__ __align__(16) unsigned short ldsB[2][2][128 * 64];

  // bijective XCD swizzle
  const int orig = blockIdx.x;
  const int q = nwg >> 3, rr = nwg & 7;
  const int xcd = orig & 7, idx = orig >> 3;
  const int wg = (xcd < rr ? xcd * (q + 1) : rr * (q + 1) + (xcd - rr) * q) + idx;
  const int mtile = wg / ntiles, ntile = wg % ntiles;

  const int t = threadIdx.x, lane = t & 63, wid = t >> 6;
  const int wm = wid >> 2, wn = wid & 3;      // 2M x 4N waves, wave tile 128x64
  const size_t Abase = (size_t)mtile * 256 * K;
  const size_t Wbase = (size_t)ntile * 256 * K;
  const int NT = K >> 6;                      // number of 64-wide K tiles (even)
  const int G = NT >> 1;

  // staging geometry: one half-tile (128x64) = 512 thr x 2 loads x 16B; linear LDS dest,
  // source col-group pre-swizzled by row (bank-uniform on both write and read sides).
  const int lr0 = t >> 3;
  const int g0 = t & 7;
  auto stageA = [&](int bb, int h, int kt) {
#pragma unroll
    for (int L = 0; L < 2; ++L) {
      const int lr = L * 64 + lr0;
      const int gs = g0 ^ (lr & 7);
      load_lds16(A + Abase + (size_t)(h * 128 + lr) * K + kt * 64 + gs * 8,
                 &ldsA[bb][h][L * 4096 + t * 8]);
    }
  };
  auto stageB = [&](int bb, int h, int kt) {
#pragma unroll
    for (int L = 0; L < 2; ++L) {
      const int lr = L * 64 + lr0;
      const int gs = g0 ^ (lr & 7);
      load_lds16(W + Wbase + (size_t)(h * 128 + lr) * K + kt * 64 + gs * 8,
                 &ldsB[bb][h][L * 4096 + t * 8]);
    }
  };

  f32x4 acc[8][4];
#pragma unroll
  for (int i = 0; i < 8; ++i)
#pragma unroll
    for (int j = 0; j < 4; ++j) acc[i][j] = (f32x4){0.f, 0.f, 0.f, 0.f};

  bf16x8 afL[8], afH[8], bf01[4], bf23[4];
  const int la = lane & 15, ls = lane >> 4;

  auto rdA = [&](int bb, int mibase, bf16x8* dst) {
#pragma unroll
    for (int m2 = 0; m2 < 4; ++m2)
#pragma unroll
      for (int kk = 0; kk < 2; ++kk) {
        const int lr = (mibase + m2) * 16 + la;               // 0..127 (wave's half = wm)
        const int g = (kk * 4 + ls) ^ (lr & 7);
        dst[m2 * 2 + kk] = *(const bf16x8*)&ldsA[bb][wm][lr * 64 + g * 8];
      }
  };
  auto rdB = [&](int bb, int nibase, bf16x8* dst) {
#pragma unroll
    for (int n2 = 0; n2 < 2; ++n2)
#pragma unroll
      for (int kk = 0; kk < 2; ++kk) {
        const int lrb = (wn & 1) * 64 + (nibase + n2) * 16 + la;  // half = wn>>1
        const int g = (kk * 4 + ls) ^ (lrb & 7);
        dst[n2 * 2 + kk] = *(const bf16x8*)&ldsB[bb][wn >> 1][lrb * 64 + g * 8];
      }
  };
  auto mm = [&](const bf16x8* af, const bf16x8* bf, int mibase, int nibase) {
    __builtin_amdgcn_s_setprio(1);
#pragma unroll
    for (int m2 = 0; m2 < 4; ++m2)
#pragma unroll
      for (int n2 = 0; n2 < 2; ++n2)
#pragma unroll
        for (int kk = 0; kk < 2; ++kk)
          acc[mibase + m2][nibase + n2] = __builtin_amdgcn_mfma_f32_16x16x32_bf16(
              af[m2 * 2 + kk], bf[n2 * 2 + kk], acc[mibase + m2][nibase + n2], 0, 0, 0);
    __builtin_amdgcn_s_setprio(0);
  };

  // prologue: tile0 full -> buf0 (8 loads); tile1 A -> buf1 (4 loads); gate tile0.
  stageA(0, 0, 0); stageA(0, 1, 0); stageB(0, 0, 0); stageB(0, 1, 0);
  stageA(1, 0, 1); stageA(1, 1, 1);
  GATE4();
  BARRIER();

  for (int g = 0; g < G; ++g) {
    const int v = 2 * g + 1;
    int w0 = 2 * g + 2; if (w0 >= NT) w0 -= NT;   // wrap keeps load counts invariant
    int w1 = 2 * g + 3; if (w1 >= NT) w1 -= NT;
    // ---- tile u = 2g (buf0) ----
    // p1
    rdA(0, 0, afL); rdB(0, 0, bf01); stageB(1, 0, v);
    BARRIER(); mm(afL, bf01, 0, 0); BARRIER();
    // p2
    rdA(0, 4, afH); stageB(1, 1, v);
    BARRIER(); mm(afH, bf01, 4, 0); BARRIER();
    // p3
    rdB(0, 2, bf23); stageA(0, 0, w0);
    BARRIER(); mm(afH, bf23, 4, 2); BARRIER();
    // p4
    stageA(0, 1, w0);
    GATE4();
    BARRIER(); mm(afL, bf23, 0, 2); BARRIER();
    // ---- tile v = 2g+1 (buf1) ----
    // p5
    rdA(1, 0, afL); rdB(1, 0, bf01); stageB(0, 0, w0);
    BARRIER(); mm(afL, bf01, 0, 0); BARRIER();
    // p6
    rdA(1, 4, afH); stageB(0, 1, w0);
    BARRIER(); mm(afH, bf01, 4, 0); BARRIER();
    // p7
    rdB(1, 2, bf23); stageA(1, 0, w1);
    BARRIER(); mm(afH, bf23, 4, 2); BARRIER();
    // p8
    stageA(1, 1, w1);
    GATE4();
    BARRIER(); mm(afL, bf23, 0, 2); BARRIER();
  }

  // epilogue: C/D layout col=lane&15, row=(lane>>4)*4+r (verified in k_gemm3)
#pragma unroll
  for (int ni = 0; ni < 4; ++ni) {
    const int col = ntile * 256 + wn * 64 + ni * 16 + la;
    const float bv = bias[col];
#pragma unroll
    for (int mi = 0; mi < 8; ++mi) {
      const int row0 = mtile * 256 + wm * 128 + mi * 16 + ls * 4;
#pragma unroll
      for (int r2 = 0; r2 < 4; ++r2)
        C[(size_t)(row0 + r2) * N + col] = f2bf(acc[mi][ni][r2] + bv);
    }
  }
}

// ---- GEMM 128x128, BK=32, triple-buffered (small shapes: proj-z, fc) ----
template <typename CT>
__global__ __launch_bounds__(256) void k_gemm3(const unsigned short* __restrict__ A,
                                               const unsigned short* __restrict__ W,
                                               const float* __restrict__ bias,
                                               CT* __restrict__ C,
                                               int N, int K, int ntiles, int nwg) {
  __shared__ __align__(16) unsigned short ldsA[3][128 * 32];
  __shared__ __align__(16) unsigned short ldsB[3][128 * 32];

  const int orig = blockIdx.x;
  const int q = nwg >> 3, r = nwg & 7;
  const int xcd = orig & 7, idx = orig >> 3;
  const int wg = (xcd < r ? xcd * (q + 1) : r * (q + 1) + (xcd - r) * q) + idx;
  const int mtile = wg / ntiles, ntile = wg % ntiles;

  const int t = threadIdx.x, lane = t & 63, wid = t >> 6;
  const int wm = wid >> 1, wn = wid & 1;
  const size_t Abase = (size_t)mtile * 128 * K;
  const size_t Wbase = (size_t)ntile * 128 * K;
  const int NT = K >> 5;

  f32x4 acc[4][4];
#pragma unroll
  for (int i = 0; i < 4; ++i)
#pragma unroll
    for (int j = 0; j < 4; ++j) acc[i][j] = (f32x4){0.f, 0.f, 0.f, 0.f};

  const int sr0 = t >> 2;
  auto stage = [&](int buf, int kt) {
#pragma unroll
    for (int it = 0; it < 2; ++it) {
      const int row = it * 64 + sr0;
      const int cl = (t & 3) ^ ((row >> 1) & 3);
      load_lds16(A + Abase + (size_t)row * K + kt * 32 + cl * 8, &ldsA[buf][it * 2048 + t * 8]);
    }
#pragma unroll
    for (int it = 0; it < 2; ++it) {
      const int row = it * 64 + sr0;
      const int cl = (t & 3) ^ ((row >> 1) & 3);
      load_lds16(W + Wbase + (size_t)row * K + kt * 32 + cl * 8, &ldsB[buf][it * 2048 + t * 8]);
    }
  };

  stage(0, 0);
  stage(1, 1);

  int cur = 0;
  for (int kt = 0; kt < NT; ++kt) {
    if (kt + 1 < NT) { GATE4(); } else { GATE0(); }
    BARRIER();
    if (kt + 2 < NT) {
      int s2 = cur + 2; if (s2 >= 3) s2 -= 3;
      stage(s2, kt + 2);
    }
    bf16x8 af[4], bfr[4];
#pragma unroll
    for (int mi = 0; mi < 4; ++mi) {
      const int row = wm * 64 + mi * 16 + (lane & 15);
      const int st = (lane >> 4) ^ ((row >> 1) & 3);
      af[mi] = *(const bf16x8*)&ldsA[cur][row * 32 + st * 8];
    }
#pragma unroll
    for (int ni = 0; ni < 4; ++ni) {
      const int row = wn * 64 + ni * 16 + (lane & 15);
      const int st = (lane >> 4) ^ ((row >> 1) & 3);
      bfr[ni] = *(const bf16x8*)&ldsB[cur][row * 32 + st * 8];
    }
#pragma unroll
    for (int mi = 0; mi < 4; ++mi)
#pragma unroll
      for (int ni = 0; ni < 4; ++ni)
        acc[mi][ni] = __builtin_amdgcn_mfma_f32_16x16x32_bf16(af[mi], bfr[ni], acc[mi][ni], 0, 0, 0);
    cur = (cur + 1 == 3) ? 0 : cur + 1;
  }

#pragma unroll
  for (int ni = 0; ni < 4; ++ni) {
    const int col = ntile * 128 + wn * 64 + ni * 16 + (lane & 15);
    const float bv = bias[col];
#pragma unroll
    for (int mi = 0; mi < 4; ++mi) {
      const int row0 = mtile * 128 + wm * 64 + mi * 16 + ((lane >> 4) << 2);
#pragma unroll
      for (int r2 = 0; r2 < 4; ++r2) {
        const float ov = acc[mi][ni][r2] + bv;
        if constexpr (sizeof(CT) == 2)
          C[(size_t)(row0 + r2) * N + col] = (CT)f2bf(ov);
        else
          C[(size_t)(row0 + r2) * N + col] = (CT)ov;
      }
    }
  }
}

// ---------------- fused attention per (b,h), 62KB static LDS ----------------
__global__ __launch_bounds__(512) void k_attn(const unsigned short* __restrict__ qkv,
                                              const unsigned int* __restrict__ bm,
                                              unsigned short* __restrict__ y,
                                              float* __restrict__ am, int b0) {
  __shared__ __align__(16) unsigned short A_lds[128 * 128];   // K, then V^T
  __shared__ __align__(16) unsigned short P_lds[7 * 16 * 128];
  __shared__ float am_s[112];
  const int t = threadIdx.x, lane = t & 63, w = t >> 6;
  const int bl = blockIdx.x >> 2, h = blockIdx.x & 3;
  const int bg = b0 + bl;
  const unsigned short* qk = qkv + (size_t)bl * 153600;

  if (t < 112) am_s[t] = 0.f;

#pragma unroll
  for (int j = 0; j < 4; ++j) {
    const int row = j * 32 + w * 4 + (lane >> 4);
    if (row < 100) {
      const int c = (lane & 15) ^ (row & 7);
      load_lds16(qk + (size_t)row * 1536 + 512 + h * 128 + c * 8,
                 &A_lds[j * 4096 + w * 512 + lane * 8]);
    }
  }
  u32x4 vv[4];
#pragma unroll
  for (int p = 0; p < 4; ++p) {
    const int vm = p * 32 + (t >> 4);
    const u32x4 z = {0u, 0u, 0u, 0u};
    vv[p] = (vm < 100) ? *(const u32x4*)(qk + (size_t)vm * 1536 + 1024 + h * 128 + (t & 15) * 8) : z;
  }
  bf16x8 qf[4];
  {
    const int qrow = w * 16 + (lane & 15);
    const bool qv = (w < 7) && (qrow < 100);
#pragma unroll
    for (int kk = 0; kk < 4; ++kk) {
      const bf16x8 z = {0, 0, 0, 0, 0, 0, 0, 0};
      qf[kk] = qv ? *(const bf16x8*)(qk + (size_t)qrow * 1536 + h * 128 + kk * 32 + (lane >> 4) * 8) : z;
    }
  }
  if (t < 192) {
    const u32x4 z = {0u, 0u, 0u, 0u};
    *(u32x4*)&A_lds[(100 + (t >> 4)) * 128 + (t & 15) * 8] = z;
  }
  __syncthreads();

  f32x4 sa[7];
#pragma unroll
  for (int ni = 0; ni < 7; ++ni) sa[ni] = (f32x4){0.f, 0.f, 0.f, 0.f};
  if (w < 7) {
#pragma unroll
    for (int kk = 0; kk < 4; ++kk)
#pragma unroll
      for (int ni = 0; ni < 7; ++ni) {
        const int row = ni * 16 + (lane & 15);
        const int c = (kk * 4 + (lane >> 4)) ^ (row & 7);
        const bf16x8 kf = *(const bf16x8*)&A_lds[row * 128 + (c << 3)];
        sa[ni] = __builtin_amdgcn_mfma_f32_16x16x32_bf16(qf[kk], kf, sa[ni], 0, 0, 0);
      }
  }
  __syncthreads();

#pragma unroll
  for (int p = 0; p < 4; ++p) {
    const int vm = p * 32 + (t >> 4);
    unsigned short tmp[8];
    *(u32x4*)tmp = vv[p];
#pragma unroll
    for (int jj = 0; jj < 8; ++jj) {
      const int d = (lane & 15) * 8 + jj;
      const int swz = (vm >> 3) ^ (((d >> 3) ^ d) & 7);
      A_lds[d * 128 + swz * 8 + (vm & 7)] = tmp[jj];
    }
  }

  if (w < 7) {
    const float scale = 0.08838834764831843f;
    float psum[7] = {0.f, 0.f, 0.f, 0.f, 0.f, 0.f, 0.f};
#pragma unroll
    for (int r = 0; r < 4; ++r) {
      const int lr = (lane >> 4) * 4 + r;
      const int qrow = w * 16 + lr;
      if (qrow < 100) {
        const u32x4 bmv = *(const u32x4*)(bm + ((size_t)bg * 100 + qrow) * 4);
        float x[7];
#pragma unroll
        for (int ni = 0; ni < 7; ++ni) {
          const int col = ni * 16 + (lane & 15);
          const unsigned int bit = (bmv[ni >> 1] >> (((ni & 1) << 4) + (lane & 15))) & 1u;
          x[ni] = (col < 100) ? (bit ? sa[ni][r] * scale : -1e9f) : -1e30f;
        }
        float mx = x[0];
#pragma unroll
        for (int ni = 1; ni < 7; ++ni) mx = fmaxf(mx, x[ni]);
#pragma unroll
        for (int dd = 1; dd < 16; dd <<= 1) mx = fmaxf(mx, __shfl_xor(mx, dd, 64));
        float e[7], sum = 0.f;
#pragma unroll
        for (int ni = 0; ni < 7; ++ni) { e[ni] = __expf(x[ni] - mx); sum += e[ni]; }
#pragma unroll
        for (int dd = 1; dd < 16; dd <<= 1) sum += __shfl_xor(sum, dd, 64);
        const float inv = 1.f / sum;
#pragma unroll
        for (int ni = 0; ni < 7; ++ni) {
          const float pv = e[ni] * inv;
          psum[ni] += pv;
          const int col = ni * 16 + (lane & 15);
          const int c = (col >> 3) ^ (lr & 7);
          P_lds[w * 2048 + lr * 128 + c * 8 + (col & 7)] = f2bf(pv);
        }
      } else {
#pragma unroll
        for (int ni = 0; ni < 7; ++ni) {
          const int col = ni * 16 + (lane & 15);
          const int c = (col >> 3) ^ (lr & 7);
          P_lds[w * 2048 + lr * 128 + c * 8 + (col & 7)] = 0;
        }
      }
    }
    if (lane < 32) {
      const int lr = lane & 15;
      const int c = (14 + (lane >> 4)) ^ (lr & 7);
      const u32x4 z = {0u, 0u, 0u, 0u};
      *(u32x4*)&P_lds[w * 2048 + lr * 128 + c * 8] = z;
    }
#pragma unroll
    for (int ni = 0; ni < 7; ++ni) atomicAdd(&am_s[ni * 16 + (lane & 15)], psum[ni]);
  }
  __syncthreads();

  if (t < 100) am[((size_t)bg * 4 + h) * 100 + t] = am_s[t] * 0.01f;

  if (w < 7) {
#pragma unroll
    for (int dt = 0; dt < 8; ++dt) {
      f32x4 acc = {0.f, 0.f, 0.f, 0.f};
#pragma unroll
      for (int kk = 0; kk < 4; ++kk) {
        const int c = kk * 4 + (lane >> 4);
        const bf16x8 pf = *(const bf16x8*)&P_lds[w * 2048 + (lane & 15) * 128 + ((c ^ (lane & 7)) << 3)];
        const int d = dt * 16 + (lane & 15);
        const int cv = c ^ (((d >> 3) ^ d) & 7);
        const bf16x8 vf = *(const bf16x8*)&A_lds[d * 128 + (cv << 3)];
        acc = __builtin_amdgcn_mfma_f32_16x16x32_bf16(pf, vf, acc, 0, 0, 0);
      }
      const int d = dt * 16 + (lane & 15);
#pragma unroll
      for (int r = 0; r < 4; ++r) {
        const int qrow = w * 16 + (lane >> 4) * 4 + r;
        if (qrow < 100)
          y[((size_t)bl * 100 + qrow) * 512 + h * 128 + d] = f2bf(acc[r]);
      }
    }
  }
}

// ---------------- z = am^T y  (per b: [4][512]) -> bf16 rows (b*4+h) ----------------
__global__ __launch_bounds__(256) void k_z(const float* __restrict__ am,
                                           const unsigned short* __restrict__ y,
                                           unsigned short* __restrict__ zb, int b0) {
  __shared__ float ams[400];
  const int bl = blockIdx.x, t = threadIdx.x;
  const int bg = b0 + bl;
  for (int i = t; i < 400; i += 256) ams[i] = am[(size_t)bg * 400 + i];
  __syncthreads();
  float a0[4] = {0, 0, 0, 0}, a1[4] = {0, 0, 0, 0};
  const unsigned short* yb = y + (size_t)bl * 100 * 512 + t * 2;
  for (int n = 0; n < 100; ++n) {
    const unsigned int u = *(const unsigned int*)(yb + (size_t)n * 512);
    const float v0 = bf2f((unsigned short)(u & 0xffffu));
    const float v1 = bf2f((unsigned short)(u >> 16));
#pragma unroll
    for (int hh = 0; hh < 4; ++hh) {
      const float ww = ams[hh * 100 + n];
      a0[hh] += ww * v0;
      a1[hh] += ww * v1;
    }
  }
#pragma unroll
  for (int hh = 0; hh < 4; ++hh) {
    const unsigned int pk = (unsigned int)f2bf(a0[hh]) | ((unsigned int)f2bf(a1[hh]) << 16);
    *(unsigned int*)(zb + ((size_t)(bl * 4 + hh)) * 512 + 2 * t) = pk;
  }
}

// ---------------- LN2 per row (wave-per-row) ----------------
__global__ __launch_bounds__(256) void k_ln2(const unsigned short* __restrict__ wcb,
                                             const float* __restrict__ g2,
                                             const float* __restrict__ b2,
                                             unsigned short* __restrict__ wcn) {
  const int t = threadIdx.x, lane = t & 63, w = t >> 6;
  const int row = blockIdx.x * 4 + w;
  const u32x4 pv = *(const u32x4*)(wcb + (size_t)row * 512 + lane * 8);
  float v[8];
#pragma unroll
  for (int j = 0; j < 4; ++j) {
    v[2 * j] = bf2f((unsigned short)(pv[j] & 0xffffu));
    v[2 * j + 1] = bf2f((unsigned short)(pv[j] >> 16));
  }
  float s = 0.f, ss = 0.f;
#pragma unroll
  for (int j = 0; j < 8; ++j) { s += v[j]; ss += v[j] * v[j]; }
#pragma unroll
  for (int d = 1; d < 64; d <<= 1) { s += __shfl_xor(s, d, 64); ss += __shfl_xor(ss, d, 64); }
  const float mu = s * (1.f / 512.f);
  const float var = ss * (1.f / 512.f) - mu * mu;
  const float rs = rsqrtf(var + 1e-5f);
  const float4 ga = *(const float4*)(g2 + lane * 8);
  const float4 gb = *(const float4*)(g2 + lane * 8 + 4);
  const float4 ba = *(const float4*)(b2 + lane * 8);
  const float4 bb = *(const float4*)(b2 + lane * 8 + 4);
  const float gv[8] = {ga.x, ga.y, ga.z, ga.w, gb.x, gb.y, gb.z, gb.w};
  const float bv[8] = {ba.x, ba.y, ba.z, ba.w, bb.x, bb.y, bb.z, bb.w};
  u32x4 ov;
#pragma unroll
  for (int j = 0; j < 4; ++j) {
    const unsigned short lo = f2bf((v[2 * j] - mu) * rs * gv[2 * j] + bv[2 * j]);
    const unsigned short hi = f2bf((v[2 * j + 1] - mu) * rs * gv[2 * j + 1] + bv[2 * j + 1]);
    ov[j] = (unsigned int)lo | ((unsigned int)hi << 16);
  }
  *(u32x4*)(wcn + (size_t)row * 512 + lane * 8) = ov;
}

extern "C" void kernel_launch(void* const* d_in, const int* in_sizes, int n_in,
                              void* d_out, int out_size, void* d_ws, size_t ws_size,
                              hipStream_t stream) {
  const int* conn = (const int*)d_in[0];
  const int* mask = (const int*)d_in[1];
  const float* emb = (const float*)d_in[2];
  const float* qkv_w = (const float*)d_in[3];
  const float* qkv_b = (const float*)d_in[4];
  const float* proj_w = (const float*)d_in[5];
  const float* proj_b = (const float*)d_in[6];
  const float* ln1g = (const float*)d_in[7];
  const float* ln1b = (const float*)d_in[8];
  const float* ln2g = (const float*)d_in[9];
  const float* ln2b = (const float*)d_in[10];
  const float* fc_w = (const float*)d_in[11];
  const float* fc_b = (const float*)d_in[12];
  float* out = (float*)d_out;

  size_t off = 0;
  auto alloc = [&](size_t bytes) {
    void* p = (char*)d_ws + off;
    off += (bytes + 255) & ~(size_t)255;
    return p;
  };
  unsigned short* w_qkv = (unsigned short*)alloc((size_t)1536 * 512 * 2);
  unsigned short* w_proj = (unsigned short*)alloc((size_t)512 * 512 * 2);
  unsigned short* w_fc = (unsigned short*)alloc((size_t)256 * 512 * 2);
  float* am = (float*)alloc((size_t)1024 * 400 * 4);
  unsigned int* bmb = (unsigned int*)alloc((size_t)102400 * 16);
  const size_t fixed = off;

  int CB = 1024;
  while (CB > 64) {
    size_t need = fixed + (size_t)CB * 4 * 512 * 2 * 3 + (size_t)CB * 100 * 512 * 2 +
                  (size_t)CB * 100 * 1536 * 2 + 8192;
    if (need <= ws_size) break;
    CB >>= 1;
  }
  unsigned short* zbuf = (unsigned short*)alloc((size_t)CB * 4 * 512 * 2);
  unsigned short* wcb = (unsigned short*)alloc((size_t)CB * 4 * 512 * 2);
  unsigned short* wcn = (unsigned short*)alloc((size_t)CB * 4 * 512 * 2);
  unsigned short* xn = (unsigned short*)alloc((size_t)CB * 100 * 512 * 2);    // also y
  unsigned short* qkvb = (unsigned short*)alloc((size_t)CB * 100 * 1536 * 2);

  k_cvt3<<<(786432 + 262144 + 131072 + 255) / 256, 256, 0, stream>>>(
      qkv_w, 786432, proj_w, 262144, fc_w, 131072, w_qkv, w_proj, w_fc);
  k_maskpack<<<1600, 256, 0, stream>>>(mask, bmb);

  for (int b0 = 0; b0 < 1024; b0 += CB) {
    const int mt256 = CB * 100 / 256;   // QKV: 256-row tiles
    const int zt = CB * 4 / 128;        // small GEMMs: 128-row tiles
    k_gather_ln<<<CB * 25, 256, 0, stream>>>(conn, emb, ln1g, ln1b, xn, b0 * 100);
    k_gemm8<<<6 * mt256, 512, 0, stream>>>(xn, w_qkv, qkv_b, qkvb, 1536, 512, 6, 6 * mt256);
    k_attn<<<CB * 4, 512, 0, stream>>>(qkvb, bmb, xn /*y*/, am, b0);
    k_z<<<CB, 256, 0, stream>>>(am, xn /*y*/, zbuf, b0);
    k_gemm3<unsigned short><<<4 * zt, 256, 0, stream>>>(zbuf, w_proj, proj_b, wcb, 512, 512, 4, 4 * zt);
    k_ln2<<<CB, 256, 0, stream>>>(wcb, ln2g, ln2b, wcn);
    k_gemm3<float><<<2 * zt, 256, 0, stream>>>(wcn, w_fc, fc_b, out + (size_t)b0 * 1024, 256, 512, 2, 2 * zt);
  }
}

// Round 8
// 538.497 us; speedup vs baseline: 1.1679x; 1.0587x over previous
//
#include <hip/hip_runtime.h>
#include <stdint.h>

typedef __attribute__((ext_vector_type(8))) short bf16x8;
typedef __attribute__((ext_vector_type(4))) float f32x4;
typedef __attribute__((ext_vector_type(4))) unsigned int u32x4;
typedef __attribute__((ext_vector_type(4))) unsigned short u16x4;

typedef const void __attribute__((address_space(1))) gvoid_t;
typedef void __attribute__((address_space(3))) lvoid_t;

__device__ __forceinline__ unsigned short f2bf(float f) {
  union { float f; unsigned int u; } v; v.f = f;
  unsigned int u = v.u;
  u += 0x7fffu + ((u >> 16) & 1u);
  return (unsigned short)(u >> 16);
}
__device__ __forceinline__ float bf2f(unsigned short h) {
  union { unsigned int u; float f; } v; v.u = ((unsigned int)h) << 16;
  return v.f;
}
__device__ __forceinline__ void load_lds16(const void* g, void* l) {
  __builtin_amdgcn_global_load_lds((gvoid_t*)g, (lvoid_t*)l, 16, 0, 0);
}

#define GATE4() asm volatile("s_waitcnt vmcnt(4)" ::: "memory")
#define GATE0() asm volatile("s_waitcnt vmcnt(0)" ::: "memory")
#define BARRIER()                    \
  do {                               \
    asm volatile("" ::: "memory");   \
    __builtin_amdgcn_s_barrier();    \
    asm volatile("" ::: "memory");   \
  } while (0)

// ---------------- prep: weights f32->bf16 + mask bitpack, one dispatch ----------------
__global__ __launch_bounds__(256) void k_prep(const float* __restrict__ s0, int n0,
                                              const float* __restrict__ s1, int n1,
                                              const float* __restrict__ s2, int n2,
                                              unsigned short* __restrict__ d0,
                                              unsigned short* __restrict__ d1,
                                              unsigned short* __restrict__ d2,
                                              const int* __restrict__ mask,
                                              unsigned int* __restrict__ bm,
                                              int ncvtblk) {
  if ((int)blockIdx.x < ncvtblk) {
    int i = blockIdx.x * 256 + threadIdx.x;
    if (i < n0) { d0[i] = f2bf(s0[i]); return; }
    i -= n0;
    if (i < n1) { d1[i] = f2bf(s1[i]); return; }
    i -= n1;
    if (i < n2) d2[i] = f2bf(s2[i]);
    return;
  }
  const int lane = threadIdx.x & 63;
  const int wv = ((blockIdx.x - ncvtblk) << 2) + (threadIdx.x >> 6);
  const int r0 = wv * 16;
  for (int i = 0; i < 16; ++i) {
    const int r = r0 + i;
    const size_t base = (size_t)r * 100;
    const int c0 = mask[base + lane];
    int c1 = 0;
    if (lane < 36) c1 = mask[base + 64 + lane];
    const unsigned long long b0 = __ballot(c0 != 0);
    const unsigned long long b1 = __ballot(c1 != 0);
    if (lane == 0) {
      u32x4 v;
      v[0] = (unsigned int)b0; v[1] = (unsigned int)(b0 >> 32);
      v[2] = (unsigned int)b1; v[3] = (unsigned int)(b1 >> 32);
      *(u32x4*)(bm + (size_t)r * 4) = v;
    }
  }
}

// ---------------- gather + LN1 -> xn bf16 [rows][512] (chunk-local) ----------------
__global__ __launch_bounds__(256) void k_gather_ln(const int* __restrict__ conn,
                                                   const float* __restrict__ emb,
                                                   const float* __restrict__ g1,
                                                   const float* __restrict__ b1,
                                                   unsigned short* __restrict__ xn,
                                                   int row0) {
  const int lane = threadIdx.x & 63;
  const int wid = threadIdx.x >> 6;
  const int rloc = blockIdx.x * 4 + wid;
  const int row = row0 + rloc;
  const int rel = conn[row * 2 + 0];
  const int ent = conn[row * 2 + 1];
  const float4 r4 = *(const float4*)(emb + (size_t)rel * 256 + lane * 4);
  const float4 e4 = *(const float4*)(emb + (size_t)ent * 256 + lane * 4);
  float rv[4] = {r4.x, r4.y, r4.z, r4.w};
  float ev[4] = {e4.x, e4.y, e4.z, e4.w};
  float s = 0.f, ss = 0.f;
#pragma unroll
  for (int j = 0; j < 4; ++j) { s += rv[j] + ev[j]; ss += rv[j] * rv[j] + ev[j] * ev[j]; }
#pragma unroll
  for (int d = 1; d < 64; d <<= 1) { s += __shfl_xor(s, d, 64); ss += __shfl_xor(ss, d, 64); }
  const float mu = s * (1.f / 512.f);
  const float var = ss * (1.f / 512.f) - mu * mu;
  const float rs = rsqrtf(var + 1e-5f);
  const float4 ga = *(const float4*)(g1 + lane * 4);
  const float4 gb = *(const float4*)(g1 + 256 + lane * 4);
  const float4 ba = *(const float4*)(b1 + lane * 4);
  const float4 bb = *(const float4*)(b1 + 256 + lane * 4);
  float gav[4] = {ga.x, ga.y, ga.z, ga.w}, gbv[4] = {gb.x, gb.y, gb.z, gb.w};
  float bav[4] = {ba.x, ba.y, ba.z, ba.w}, bbv[4] = {bb.x, bb.y, bb.z, bb.w};
  u16x4 o0, o1;
#pragma unroll
  for (int j = 0; j < 4; ++j) {
    o0[j] = f2bf((rv[j] - mu) * rs * gav[j] + bav[j]);
    o1[j] = f2bf((ev[j] - mu) * rs * gbv[j] + bbv[j]);
  }
  unsigned short* orow = xn + (size_t)rloc * 512;
  *(u16x4*)(orow + lane * 4) = o0;
  *(u16x4*)(orow + 256 + lane * 4) = o1;
}

// ---- GEMM 128x128, BK=32, triple-buffered, counted vmcnt, raw barrier (R4-verified) ----
template <typename CT>
__global__ __launch_bounds__(256) void k_gemm3(const unsigned short* __restrict__ A,
                                               const unsigned short* __restrict__ W,
                                               const float* __restrict__ bias,
                                               CT* __restrict__ C,
                                               int N, int K, int ntiles, int nwg) {
  __shared__ __align__(16) unsigned short ldsA[3][128 * 32];
  __shared__ __align__(16) unsigned short ldsB[3][128 * 32];

  const int orig = blockIdx.x;
  const int q = nwg >> 3, r = nwg & 7;
  const int xcd = orig & 7, idx = orig >> 3;
  const int wg = (xcd < r ? xcd * (q + 1) : r * (q + 1) + (xcd - r) * q) + idx;
  const int mtile = wg / ntiles, ntile = wg % ntiles;

  const int t = threadIdx.x, lane = t & 63, wid = t >> 6;
  const int wm = wid >> 1, wn = wid & 1;
  const size_t Abase = (size_t)mtile * 128 * K;
  const size_t Wbase = (size_t)ntile * 128 * K;
  const int NT = K >> 5;

  f32x4 acc[4][4];
#pragma unroll
  for (int i = 0; i < 4; ++i)
#pragma unroll
    for (int j = 0; j < 4; ++j) acc[i][j] = (f32x4){0.f, 0.f, 0.f, 0.f};

  const int sr0 = t >> 2;
  auto stage = [&](int buf, int kt) {
#pragma unroll
    for (int it = 0; it < 2; ++it) {
      const int row = it * 64 + sr0;
      const int cl = (t & 3) ^ ((row >> 1) & 3);
      load_lds16(A + Abase + (size_t)row * K + kt * 32 + cl * 8, &ldsA[buf][it * 2048 + t * 8]);
    }
#pragma unroll
    for (int it = 0; it < 2; ++it) {
      const int row = it * 64 + sr0;
      const int cl = (t & 3) ^ ((row >> 1) & 3);
      load_lds16(W + Wbase + (size_t)row * K + kt * 32 + cl * 8, &ldsB[buf][it * 2048 + t * 8]);
    }
  };

  stage(0, 0);
  stage(1, 1);

  int cur = 0;
  for (int kt = 0; kt < NT; ++kt) {
    if (kt + 1 < NT) { GATE4(); } else { GATE0(); }
    BARRIER();
    if (kt + 2 < NT) {
      int s2 = cur + 2; if (s2 >= 3) s2 -= 3;
      stage(s2, kt + 2);
    }
    bf16x8 af[4], bfr[4];
#pragma unroll
    for (int mi = 0; mi < 4; ++mi) {
      const int row = wm * 64 + mi * 16 + (lane & 15);
      const int st = (lane >> 4) ^ ((row >> 1) & 3);
      af[mi] = *(const bf16x8*)&ldsA[cur][row * 32 + st * 8];
    }
#pragma unroll
    for (int ni = 0; ni < 4; ++ni) {
      const int row = wn * 64 + ni * 16 + (lane & 15);
      const int st = (lane >> 4) ^ ((row >> 1) & 3);
      bfr[ni] = *(const bf16x8*)&ldsB[cur][row * 32 + st * 8];
    }
#pragma unroll
    for (int mi = 0; mi < 4; ++mi)
#pragma unroll
      for (int ni = 0; ni < 4; ++ni)
        acc[mi][ni] = __builtin_amdgcn_mfma_f32_16x16x32_bf16(af[mi], bfr[ni], acc[mi][ni], 0, 0, 0);
    cur = (cur + 1 == 3) ? 0 : cur + 1;
  }

#pragma unroll
  for (int ni = 0; ni < 4; ++ni) {
    const int col = ntile * 128 + wn * 64 + ni * 16 + (lane & 15);
    const float bv = bias[col];
#pragma unroll
    for (int mi = 0; mi < 4; ++mi) {
      const int row0 = mtile * 128 + wm * 64 + mi * 16 + ((lane >> 4) << 2);
#pragma unroll
      for (int r2 = 0; r2 < 4; ++r2) {
        const float ov = acc[mi][ni][r2] + bv;
        if constexpr (sizeof(CT) == 2)
          C[(size_t)(row0 + r2) * N + col] = (CT)f2bf(ov);
        else
          C[(size_t)(row0 + r2) * N + col] = (CT)ov;
      }
    }
  }
}

// ---------------- fused attention per (b,h), 62KB static LDS ----------------
__global__ __launch_bounds__(512) void k_attn(const unsigned short* __restrict__ qkv,
                                              const unsigned int* __restrict__ bm,
                                              unsigned short* __restrict__ y,
                                              float* __restrict__ am, int b0) {
  __shared__ __align__(16) unsigned short A_lds[128 * 128];   // K, then V^T
  __shared__ __align__(16) unsigned short P_lds[7 * 16 * 128];
  __shared__ float am_s[112];
  const int t = threadIdx.x, lane = t & 63, w = t >> 6;
  const int bl = blockIdx.x >> 2, h = blockIdx.x & 3;
  const int bg = b0 + bl;
  const unsigned short* qk = qkv + (size_t)bl * 153600;

  if (t < 112) am_s[t] = 0.f;

#pragma unroll
  for (int j = 0; j < 4; ++j) {
    const int row = j * 32 + w * 4 + (lane >> 4);
    if (row < 100) {
      const int c = (lane & 15) ^ (row & 7);
      load_lds16(qk + (size_t)row * 1536 + 512 + h * 128 + c * 8,
                 &A_lds[j * 4096 + w * 512 + lane * 8]);
    }
  }
  u32x4 vv[4];
#pragma unroll
  for (int p = 0; p < 4; ++p) {
    const int vm = p * 32 + (t >> 4);
    const u32x4 z = {0u, 0u, 0u, 0u};
    vv[p] = (vm < 100) ? *(const u32x4*)(qk + (size_t)vm * 1536 + 1024 + h * 128 + (t & 15) * 8) : z;
  }
  bf16x8 qf[4];
  {
    const int qrow = w * 16 + (lane & 15);
    const bool qv = (w < 7) && (qrow < 100);
#pragma unroll
    for (int kk = 0; kk < 4; ++kk) {
      const bf16x8 z = {0, 0, 0, 0, 0, 0, 0, 0};
      qf[kk] = qv ? *(const bf16x8*)(qk + (size_t)qrow * 1536 + h * 128 + kk * 32 + (lane >> 4) * 8) : z;
    }
  }
  if (t < 192) {
    const u32x4 z = {0u, 0u, 0u, 0u};
    *(u32x4*)&A_lds[(100 + (t >> 4)) * 128 + (t & 15) * 8] = z;
  }
  __syncthreads();

  f32x4 sa[7];
#pragma unroll
  for (int ni = 0; ni < 7; ++ni) sa[ni] = (f32x4){0.f, 0.f, 0.f, 0.f};
  if (w < 7) {
#pragma unroll
    for (int kk = 0; kk < 4; ++kk)
#pragma unroll
      for (int ni = 0; ni < 7; ++ni) {
        const int row = ni * 16 + (lane & 15);
        const int c = (kk * 4 + (lane >> 4)) ^ (row & 7);
        const bf16x8 kf = *(const bf16x8*)&A_lds[row * 128 + (c << 3)];
        sa[ni] = __builtin_amdgcn_mfma_f32_16x16x32_bf16(qf[kk], kf, sa[ni], 0, 0, 0);
      }
  }
  __syncthreads();

#pragma unroll
  for (int p = 0; p < 4; ++p) {
    const int vm = p * 32 + (t >> 4);
    unsigned short tmp[8];
    *(u32x4*)tmp = vv[p];
#pragma unroll
    for (int jj = 0; jj < 8; ++jj) {
      const int d = (lane & 15) * 8 + jj;
      const int swz = (vm >> 3) ^ (((d >> 3) ^ d) & 7);
      A_lds[d * 128 + swz * 8 + (vm & 7)] = tmp[jj];
    }
  }

  if (w < 7) {
    const float scale = 0.08838834764831843f;
    float psum[7] = {0.f, 0.f, 0.f, 0.f, 0.f, 0.f, 0.f};
#pragma unroll
    for (int r = 0; r < 4; ++r) {
      const int lr = (lane >> 4) * 4 + r;
      const int qrow = w * 16 + lr;
      if (qrow < 100) {
        const u32x4 bmv = *(const u32x4*)(bm + ((size_t)bg * 100 + qrow) * 4);
        float x[7];
#pragma unroll
        for (int ni = 0; ni < 7; ++ni) {
          const int col = ni * 16 + (lane & 15);
          const unsigned int bit = (bmv[ni >> 1] >> (((ni & 1) << 4) + (lane & 15))) & 1u;
          x[ni] = (col < 100) ? (bit ? sa[ni][r] * scale : -1e9f) : -1e30f;
        }
        float mx = x[0];
#pragma unroll
        for (int ni = 1; ni < 7; ++ni) mx = fmaxf(mx, x[ni]);
#pragma unroll
        for (int dd = 1; dd < 16; dd <<= 1) mx = fmaxf(mx, __shfl_xor(mx, dd, 64));
        float e[7], sum = 0.f;
#pragma unroll
        for (int ni = 0; ni < 7; ++ni) { e[ni] = __expf(x[ni] - mx); sum += e[ni]; }
#pragma unroll
        for (int dd = 1; dd < 16; dd <<= 1) sum += __shfl_xor(sum, dd, 64);
        const float inv = 1.f / sum;
#pragma unroll
        for (int ni = 0; ni < 7; ++ni) {
          const float pv = e[ni] * inv;
          psum[ni] += pv;
          const int col = ni * 16 + (lane & 15);
          const int c = (col >> 3) ^ (lr & 7);
          P_lds[w * 2048 + lr * 128 + c * 8 + (col & 7)] = f2bf(pv);
        }
      } else {
#pragma unroll
        for (int ni = 0; ni < 7; ++ni) {
          const int col = ni * 16 + (lane & 15);
          const int c = (col >> 3) ^ (lr & 7);
          P_lds[w * 2048 + lr * 128 + c * 8 + (col & 7)] = 0;
        }
      }
    }
    if (lane < 32) {
      const int lr = lane & 15;
      const int c = (14 + (lane >> 4)) ^ (lr & 7);
      const u32x4 z = {0u, 0u, 0u, 0u};
      *(u32x4*)&P_lds[w * 2048 + lr * 128 + c * 8] = z;
    }
#pragma unroll
    for (int ni = 0; ni < 7; ++ni) atomicAdd(&am_s[ni * 16 + (lane & 15)], psum[ni]);
  }
  __syncthreads();

  if (t < 100) am[((size_t)bg * 4 + h) * 100 + t] = am_s[t] * 0.01f;

  if (w < 7) {
#pragma unroll
    for (int dt = 0; dt < 8; ++dt) {
      f32x4 acc = {0.f, 0.f, 0.f, 0.f};
#pragma unroll
      for (int kk = 0; kk < 4; ++kk) {
        const int c = kk * 4 + (lane >> 4);
        const bf16x8 pf = *(const bf16x8*)&P_lds[w * 2048 + (lane & 15) * 128 + ((c ^ (lane & 7)) << 3)];
        const int d = dt * 16 + (lane & 15);
        const int cv = c ^ (((d >> 3) ^ d) & 7);
        const bf16x8 vf = *(const bf16x8*)&A_lds[d * 128 + (cv << 3)];
        acc = __builtin_amdgcn_mfma_f32_16x16x32_bf16(pf, vf, acc, 0, 0, 0);
      }
      const int d = dt * 16 + (lane & 15);
#pragma unroll
      for (int r = 0; r < 4; ++r) {
        const int qrow = w * 16 + (lane >> 4) * 4 + r;
        if (qrow < 100)
          y[((size_t)bl * 100 + qrow) * 512 + h * 128 + d] = f2bf(acc[r]);
      }
    }
  }
}

// ---------------- z = am^T y  (per b: [4][512]) -> bf16 rows (b*4+h) ----------------
__global__ __launch_bounds__(256) void k_z(const float* __restrict__ am,
                                           const unsigned short* __restrict__ y,
                                           unsigned short* __restrict__ zb, int b0) {
  __shared__ float ams[400];
  const int bl = blockIdx.x, t = threadIdx.x;
  const int bg = b0 + bl;
  for (int i = t; i < 400; i += 256) ams[i] = am[(size_t)bg * 400 + i];
  __syncthreads();
  float a0[4] = {0, 0, 0, 0}, a1[4] = {0, 0, 0, 0};
  const unsigned short* yb = y + (size_t)bl * 100 * 512 + t * 2;
#pragma unroll 4
  for (int n = 0; n < 100; ++n) {
    const unsigned int u = *(const unsigned int*)(yb + (size_t)n * 512);
    const float v0 = bf2f((unsigned short)(u & 0xffffu));
    const float v1 = bf2f((unsigned short)(u >> 16));
#pragma unroll
    for (int hh = 0; hh < 4; ++hh) {
      const float ww = ams[hh * 100 + n];
      a0[hh] += ww * v0;
      a1[hh] += ww * v1;
    }
  }
#pragma unroll
  for (int hh = 0; hh < 4; ++hh) {
    const unsigned int pk = (unsigned int)f2bf(a0[hh]) | ((unsigned int)f2bf(a1[hh]) << 16);
    *(unsigned int*)(zb + ((size_t)(bl * 4 + hh)) * 512 + 2 * t) = pk;
  }
}

// ---------------- LN2 per row (wave-per-row) ----------------
__global__ __launch_bounds__(256) void k_ln2(const unsigned short* __restrict__ wcb,
                                             const float* __restrict__ g2,
                                             const float* __restrict__ b2,
                                             unsigned short* __restrict__ wcn) {
  const int t = threadIdx.x, lane = t & 63, w = t >> 6;
  const int row = blockIdx.x * 4 + w;
  const u32x4 pv = *(const u32x4*)(wcb + (size_t)row * 512 + lane * 8);
  float v[8];
#pragma unroll
  for (int j = 0; j < 4; ++j) {
    v[2 * j] = bf2f((unsigned short)(pv[j] & 0xffffu));
    v[2 * j + 1] = bf2f((unsigned short)(pv[j] >> 16));
  }
  float s = 0.f, ss = 0.f;
#pragma unroll
  for (int j = 0; j < 8; ++j) { s += v[j]; ss += v[j] * v[j]; }
#pragma unroll
  for (int d = 1; d < 64; d <<= 1) { s += __shfl_xor(s, d, 64); ss += __shfl_xor(ss, d, 64); }
  const float mu = s * (1.f / 512.f);
  const float var = ss * (1.f / 512.f) - mu * mu;
  const float rs = rsqrtf(var + 1e-5f);
  const float4 ga = *(const float4*)(g2 + lane * 8);
  const float4 gb = *(const float4*)(g2 + lane * 8 + 4);
  const float4 ba = *(const float4*)(b2 + lane * 8);
  const float4 bb = *(const float4*)(b2 + lane * 8 + 4);
  const float gv[8] = {ga.x, ga.y, ga.z, ga.w, gb.x, gb.y, gb.z, gb.w};
  const float bv[8] = {ba.x, ba.y, ba.z, ba.w, bb.x, bb.y, bb.z, bb.w};
  u32x4 ov;
#pragma unroll
  for (int j = 0; j < 4; ++j) {
    const unsigned short lo = f2bf((v[2 * j] - mu) * rs * gv[2 * j] + bv[2 * j]);
    const unsigned short hi = f2bf((v[2 * j + 1] - mu) * rs * gv[2 * j + 1] + bv[2 * j + 1]);
    ov[j] = (unsigned int)lo | ((unsigned int)hi << 16);
  }
  *(u32x4*)(wcn + (size_t)row * 512 + lane * 8) = ov;
}

extern "C" void kernel_launch(void* const* d_in, const int* in_sizes, int n_in,
                              void* d_out, int out_size, void* d_ws, size_t ws_size,
                              hipStream_t stream) {
  const int* conn = (const int*)d_in[0];
  const int* mask = (const int*)d_in[1];
  const float* emb = (const float*)d_in[2];
  const float* qkv_w = (const float*)d_in[3];
  const float* qkv_b = (const float*)d_in[4];
  const float* proj_w = (const float*)d_in[5];
  const float* proj_b = (const float*)d_in[6];
  const float* ln1g = (const float*)d_in[7];
  const float* ln1b = (const float*)d_in[8];
  const float* ln2g = (const float*)d_in[9];
  const float* ln2b = (const float*)d_in[10];
  const float* fc_w = (const float*)d_in[11];
  const float* fc_b = (const float*)d_in[12];
  float* out = (float*)d_out;

  size_t off = 0;
  auto alloc = [&](size_t bytes) {
    void* p = (char*)d_ws + off;
    off += (bytes + 255) & ~(size_t)255;
    return p;
  };
  unsigned short* w_qkv = (unsigned short*)alloc((size_t)1536 * 512 * 2);
  unsigned short* w_proj = (unsigned short*)alloc((size_t)512 * 512 * 2);
  unsigned short* w_fc = (unsigned short*)alloc((size_t)256 * 512 * 2);
  float* am = (float*)alloc((size_t)1024 * 400 * 4);
  unsigned int* bmb = (unsigned int*)alloc((size_t)102400 * 16);
  const size_t fixed = off;

  int CB = 1024;
  while (CB > 64) {
    size_t need = fixed + (size_t)CB * 4 * 512 * 2 * 3 + (size_t)CB * 100 * 512 * 2 +
                  (size_t)CB * 100 * 1536 * 2 + 8192;
    if (need <= ws_size) break;
    CB >>= 1;
  }
  unsigned short* zbuf = (unsigned short*)alloc((size_t)CB * 4 * 512 * 2);
  unsigned short* wcb = (unsigned short*)alloc((size_t)CB * 4 * 512 * 2);
  unsigned short* wcn = (unsigned short*)alloc((size_t)CB * 4 * 512 * 2);
  unsigned short* xn = (unsigned short*)alloc((size_t)CB * 100 * 512 * 2);    // also y
  unsigned short* qkvb = (unsigned short*)alloc((size_t)CB * 100 * 1536 * 2);

  const int ncvtblk = (786432 + 262144 + 131072 + 255) / 256;
  k_prep<<<ncvtblk + 1600, 256, 0, stream>>>(qkv_w, 786432, proj_w, 262144, fc_w, 131072,
                                             w_qkv, w_proj, w_fc, mask, bmb, ncvtblk);

  for (int b0 = 0; b0 < 1024; b0 += CB) {
    const int mt = CB * 100 / 128;   // QKV: 128-row tiles
    const int zt = CB * 4 / 128;     // small GEMMs: 128-row tiles
    k_gather_ln<<<CB * 25, 256, 0, stream>>>(conn, emb, ln1g, ln1b, xn, b0 * 100);
    k_gemm3<unsigned short><<<12 * mt, 256, 0, stream>>>(xn, w_qkv, qkv_b, qkvb, 1536, 512, 12, 12 * mt);
    k_attn<<<CB * 4, 512, 0, stream>>>(qkvb, bmb, xn /*y*/, am, b0);
    k_z<<<CB, 256, 0, stream>>>(am, xn /*y*/, zbuf, b0);
    k_gemm3<unsigned short><<<4 * zt, 256, 0, stream>>>(zbuf, w_proj, proj_b, wcb, 512, 512, 4, 4 * zt);
    k_ln2<<<CB, 256, 0, stream>>>(wcb, ln2g, ln2b, wcn);
    k_gemm3<float><<<2 * zt, 256, 0, stream>>>(wcn, w_fc, fc_b, out + (size_t)b0 * 1024, 256, 512, 2, 2 * zt);
  }
}